// Round 10
// baseline (471.999 us; speedup 1.0000x reference)
//
#include <hip/hip_runtime.h>
#include <hip/hip_bf16.h>

#define N_NODES  50000
#define N_EDGES  800000
#define ND       64
#define ED       32
#define MSGD     128
#define HIDD     256
#define N_AGENTS 25000
#define EPAD     800064   // N_EDGES + 64 (tile padding)
#define RPB      25       // receivers per edge-MLP block (1000 blocks)

typedef _Float16 f16;
typedef __attribute__((ext_vector_type(4))) _Float16 f16x4;
typedef __attribute__((ext_vector_type(8))) _Float16 f16x8;
typedef __attribute__((ext_vector_type(4))) float f32x4;
typedef unsigned short u16;
typedef unsigned int   u32;
typedef unsigned long long u64;

// ============================================================================
// compact + nf->f16 + weight pack fused.
// Blocks [0, 3125): compact path. Blocks [3125, 3209): pack path.
// ============================================================================
__global__ __launch_bounds__(256) void compact_pack_kernel(
    const int* __restrict__ recv, const float* __restrict__ nf,
    f16* __restrict__ nf16, int* __restrict__ rankb, int* __restrict__ deg,
    const float* __restrict__ W1, const float* __restrict__ W2,
    const float* __restrict__ Wh1, const float* __restrict__ Wh2,
    f16* __restrict__ F1, f16* __restrict__ F2,
    f16* __restrict__ F3, f16* __restrict__ F4)
{
    int b = blockIdx.x;
    if (b >= N_EDGES / 256) {
        // frag for 16x16x32: lane l, elem j <-> W[k=ks*32+(l>>4)*8+j][n=nt*16+(l&15)]
        int tid  = (b - N_EDGES / 256) * 256 + threadIdx.x;
        int grp  = tid >> 6, lane = tid & 63;
        const float* W; f16* D; int NT, stride, gl;
        if      (grp < 80)  { W = W1;  D = F1; NT = 16; stride = 256; gl = grp; }
        else if (grp < 144) { W = W2;  D = F2; NT = 8;  stride = 128; gl = grp - 80; }
        else if (grp < 208) { W = Wh1; D = F3; NT = 16; stride = 256; gl = grp - 144; }
        else if (grp < 336) { W = Wh2; D = F4; NT = 16; stride = 256; gl = grp - 208; }
        else return;
        int ks = gl / NT, nt = gl - ks * NT;
        int n  = nt * 16 + (lane & 15);
        int k0 = ks * 32 + (lane >> 4) * 8;
        f16* dst = D + ((size_t)gl * 64 + lane) * 8;
        #pragma unroll
        for (int j = 0; j < 8; ++j)
            dst[j] = (f16)W[(size_t)(k0 + j) * stride + n];
        return;
    }
    int i = b * 256 + threadIdx.x;
    {   // nf -> f16 (coalesced float4 read, f16x4 write)
        float4 v = ((const float4*)nf)[i];
        f16x4 h;
        h.x = (f16)v.x; h.y = (f16)v.y; h.z = (f16)v.z; h.w = (f16)v.w;
        ((f16x4*)nf16)[i] = h;
    }
    int r = recv[i];
    if (r < N_AGENTS)
        rankb[i] = atomicAdd(&deg[r], 1);   // 25k addresses, pipelined (R14)
}

// ============================================================================
// prefix: exclusive scan deg -> off[25001] (single block)
// ============================================================================
__global__ __launch_bounds__(1024) void prefix_kernel(
    const int* __restrict__ deg, int* __restrict__ off)
{
    __shared__ int part[1024];
    int t = threadIdx.x;
    int i0 = t * 25;
    int s = 0;
    #pragma unroll 1
    for (int i = 0; i < 25; ++i) {
        int idx = i0 + i;
        if (idx < N_AGENTS) s += deg[idx];
    }
    part[t] = s;
    __syncthreads();
    for (int d = 1; d < 1024; d <<= 1) {
        int v = (t >= d) ? part[t - d] : 0;
        __syncthreads();
        part[t] += v;
        __syncthreads();
    }
    int run = (t == 0) ? 0 : part[t - 1];
    #pragma unroll 1
    for (int i = 0; i < 25; ++i) {
        int idx = i0 + i;
        if (idx < N_AGENTS) {
            off[idx] = run;
            run += deg[idx];
        }
    }
    if (t == 1023) off[N_AGENTS] = part[1023];
}

// ============================================================================
// scatter (no atomics): iterate ALL edges; pos = off[recv] + rankb.
// ============================================================================
__global__ __launch_bounds__(256) void scatter_kernel(
    const int* __restrict__ recv, const int* __restrict__ send,
    const int* __restrict__ rankb, const int* __restrict__ off,
    int* __restrict__ eidb, int* __restrict__ sendb, int* __restrict__ recvb)
{
    int i = blockIdx.x * 256 + threadIdx.x;
    int r = recv[i];
    if (r < N_AGENTS) {
        int pos = off[r] + rankb[i];
        eidb[pos]  = i;
        sendb[pos] = send[i];
        recvb[pos] = r;
    }
}

// ============================================================================
// Edge MLP + owned aggregation, de-serialized tail (R20).
// R19 post-mortem: 227 us; tail cost dominated by SERIALIZATION, not ops:
// 1-wave gate section + extra B2b barrier + evt/recvt LDS round trip +
// 511-block straggler tail. R20:
//  - gate partials stored TRANSPOSED lpT[32][9] (pad 9: 9 coprime 32 ->
//    per-lane row reads conflict-free). After B2, ALL lanes of ALL waves
//    redundantly compute their row's logit + expf -> e,r live in registers
//    of every wave; accumulate uses __shfl, no LDS, no barrier. B2b GONE.
//  - recvt free-ride: the staging thread that loads recvb (g==8) also drops
//    the id into recvt3[(t+1)%3][e]. Triple-buffered (tail reads t%3 after
//    B2; slot rewritten only at t+2's staging, behind B1@t+1). Staging
//    GLOBAL access pattern unchanged (curse gate: FETCH must stay ~53 MB).
//  - RPB 49->25 (grid 1000): better load balance, agg_lds 24.5->12.8 KB.
// Staging + MFMA phases byte-identical to R14. HARD RULE (R8/R9/R15):
// staging = combined load+ds_write ROLLED loop + __syncthreads (B1/B2).
// ============================================================================
__global__ __launch_bounds__(512, 4) void edge_mlp_mfma(
    const f16* __restrict__ nf16, const float* __restrict__ ef,
    const f16* __restrict__ F1, const f16* __restrict__ F2,
    const float* __restrict__ b1, const float* __restrict__ b2,
    const float* __restrict__ wg, const float* __restrict__ bg,
    const int* __restrict__ sendb, const int* __restrict__ recvb,
    const int* __restrict__ eidb, const int* __restrict__ off,
    float* __restrict__ aggr, float* __restrict__ den)
{
    __shared__ __align__(16) f16 XF[2][10][64][8];  // 20 KB (double buffer)
    __shared__ __align__(16) f16 HB[16][64][8];     // 16 KB
    __shared__ __align__(16) f16 msgt[32][136];     // 8.5 KB
    __shared__ float lpT[32][9];                    // 1.1 KB (transposed+pad)
    __shared__ int   recvt3[3][32];                 // 384 B (triple buffer)
    __shared__ float agg_lds[RPB][128];             // 12.8 KB
    __shared__ float den_lds[RPB];

    const int tid  = threadIdx.x;
    const int wv   = tid >> 6;
    const int lane = tid & 63;
    const int q    = lane >> 4;
    const int li   = lane & 15;

    // ---- owned receiver range -> contiguous CSR edge range ----
    const int rb0 = blockIdx.x * RPB;
    if (rb0 >= N_AGENTS) return;
    const int rb1 = min(rb0 + RPB, N_AGENTS);
    const int eb0 = off[rb0];
    const int eb1 = off[rb1];
    const int ntiles = (eb1 - eb0 + 31) >> 5;

    // zero the block accumulator
    for (int idx = tid; idx < RPB * 128; idx += 512)
        agg_lds[idx >> 7][idx & 127] = 0.f;
    if (tid < RPB) den_lds[tid] = 0.f;

    // stationary weight fragments: W1 2 col-tiles + W2 1 col-tile per wave
    f16x8 w1[2][5], w2[8];
    #pragma unroll
    for (int ntl = 0; ntl < 2; ++ntl)
        #pragma unroll
        for (int ks = 0; ks < 5; ++ks)
            w1[ntl][ks] = *(const f16x8*)(F1 + (((size_t)(ks * 16 + 2 * wv + ntl)) * 64 + lane) * 8);
    #pragma unroll
    for (int ks = 0; ks < 8; ++ks)
        w2[ks] = *(const f16x8*)(F2 + (((size_t)(ks * 8 + wv)) * 64 + lane) * 8);

    const float4 ba  = *(const float4*)&b1[wv * 32 + q * 4];
    const float4 bb  = *(const float4*)&b1[wv * 32 + 16 + q * 4];
    const float4 bc  = *(const float4*)&b2[wv * 16 + q * 4];
    const float4 wg4 = *(const float4*)&wg[wv * 16 + q * 4];
    const float  bgv = bg[0];

    // ---- prologue: stage first tile into XF[0] (R10 idiom — rolled) ----
    if (ntiles > 0) {
        const int e0p = eb0;
        f16 (*XFd)[64][8] = XF[0];
        for (int idx = tid; idx < 768; idx += 512) {
            int e = idx / 24, g = idx - e * 24;
            int cp = e0p + e;
            if (g < 16) {
                int node = (g < 8) ? sendb[cp] : recvb[cp];
                f16x8 h = *(const f16x8*)(nf16 + (size_t)node * 64 + (g & 7) * 8);
                int slt = (e >> 4) * 5 + (g >> 2);
                int ln  = (e & 15) + 16 * (g & 3);
                *(f16x8*)&XFd[slt][ln][0] = h;
                if (g == 8) recvt3[0][e] = node;
            } else {
                int eid = eidb[cp];
                float4 v = ((const float4*)ef)[(size_t)eid * 8 + (g - 16)];
                int k0  = 128 + (g - 16) * 4;
                int slt = (e >> 4) * 5 + 4;
                int ln  = (e & 15) + 16 * ((k0 & 31) >> 3);
                int j0  = k0 & 7;
                f16x4 h;
                h.x = (f16)v.x; h.y = (f16)v.y; h.z = (f16)v.z; h.w = (f16)v.w;
                *(f16x4*)&XFd[slt][ln][j0] = h;
            }
        }
    }
    __syncthreads();

    int p = 0;
    for (int t = 0; t < ntiles; ++t) {
        const int e0 = eb0 + t * 32;
        const int tm = t % 3;

        // ---- stage NEXT tile into XF[p^1] — no barrier before layer1 ----
        if (t + 1 < ntiles) {
            const int e0n = e0 + 32;
            const int nb  = (t + 1) % 3;
            f16 (*XFd)[64][8] = XF[p ^ 1];
            for (int idx = tid; idx < 768; idx += 512) {
                int e = idx / 24, g = idx - e * 24;
                int cp = e0n + e;
                if (g < 16) {
                    int node = (g < 8) ? sendb[cp] : recvb[cp];
                    f16x8 h = *(const f16x8*)(nf16 + (size_t)node * 64 + (g & 7) * 8);
                    int slt = (e >> 4) * 5 + (g >> 2);
                    int ln  = (e & 15) + 16 * (g & 3);
                    *(f16x8*)&XFd[slt][ln][0] = h;
                    if (g == 8) recvt3[nb][e] = node;
                } else {
                    int eid = eidb[cp];
                    float4 v = ((const float4*)ef)[(size_t)eid * 8 + (g - 16)];
                    int k0  = 128 + (g - 16) * 4;
                    int slt = (e >> 4) * 5 + 4;
                    int ln  = (e & 15) + 16 * ((k0 & 31) >> 3);
                    int j0  = k0 & 7;
                    f16x4 h;
                    h.x = (f16)v.x; h.y = (f16)v.y; h.z = (f16)v.z; h.w = (f16)v.w;
                    *(f16x4*)&XFd[slt][ln][j0] = h;
                }
            }
        }

        // ---- layer 1: h[col][edge] = W1^T x^T (from XF[p]) ----
        f32x4 acc[2][2];   // [eh][ntl]
        acc[0][0] = f32x4{ba.x, ba.y, ba.z, ba.w}; acc[1][0] = acc[0][0];
        acc[0][1] = f32x4{bb.x, bb.y, bb.z, bb.w}; acc[1][1] = acc[0][1];
        #pragma unroll
        for (int ks = 0; ks < 5; ++ks)
            #pragma unroll
            for (int eh = 0; eh < 2; ++eh) {
                f16x8 xh = *(const f16x8*)XF[p][eh * 5 + ks][lane];
                acc[eh][0] = __builtin_amdgcn_mfma_f32_16x16x32_f16(w1[0][ks], xh, acc[eh][0], 0, 0, 0);
                acc[eh][1] = __builtin_amdgcn_mfma_f32_16x16x32_f16(w1[1][ks], xh, acc[eh][1], 0, 0, 0);
            }
        // relu + stash h as layer-2 B frags
        #pragma unroll
        for (int eh = 0; eh < 2; ++eh)
            #pragma unroll
            for (int ntl = 0; ntl < 2; ++ntl) {
                f16x4 hv;
                hv.x = (f16)fmaxf(acc[eh][ntl][0], 0.f);
                hv.y = (f16)fmaxf(acc[eh][ntl][1], 0.f);
                hv.z = (f16)fmaxf(acc[eh][ntl][2], 0.f);
                hv.w = (f16)fmaxf(acc[eh][ntl][3], 0.f);
                int l2 = li + 16 * (2 * ntl + (q >> 1));
                int j0 = (q & 1) * 4;
                *(f16x4*)&HB[eh * 8 + wv][l2][j0] = hv;
            }
        __syncthreads();   // B1: HB ready; XF[p^1]/recvt3 staged

        // ---- layer 2: msg[col][edge] = W2^T h^T ----
        f32x4 acc2[2];
        acc2[0] = f32x4{bc.x, bc.y, bc.z, bc.w}; acc2[1] = acc2[0];
        #pragma unroll
        for (int ks2 = 0; ks2 < 8; ++ks2)
            #pragma unroll
            for (int eh = 0; eh < 2; ++eh) {
                f16x8 hh = *(const f16x8*)HB[eh * 8 + ks2][lane];
                acc2[eh] = __builtin_amdgcn_mfma_f32_16x16x32_f16(w2[ks2], hh, acc2[eh], 0, 0, 0);
            }
        // relu + gate partial (transposed) + msg stash
        {
            float pr[2];
            #pragma unroll
            for (int eh = 0; eh < 2; ++eh) {
                float v0 = fmaxf(acc2[eh][0], 0.f);
                float v1 = fmaxf(acc2[eh][1], 0.f);
                float v2 = fmaxf(acc2[eh][2], 0.f);
                float v3 = fmaxf(acc2[eh][3], 0.f);
                f16x4 mm;
                mm.x = (f16)v0; mm.y = (f16)v1; mm.z = (f16)v2; mm.w = (f16)v3;
                *(f16x4*)&msgt[eh * 16 + li][wv * 16 + q * 4] = mm;
                float pp = v0 * wg4.x + v1 * wg4.y + v2 * wg4.z + v3 * wg4.w;
                pp += __shfl_xor(pp, 16, 64);
                pp += __shfl_xor(pp, 32, 64);
                pr[eh] = pp;
            }
            if (lane < 16) {
                lpT[li][wv]      = pr[0];
                lpT[16 + li][wv] = pr[1];
            }
        }
        __syncthreads();   // B2: msgt/lpT ready

        // ---- de-serialized tail: every lane computes its row's e,r ----
        {
            const int row = lane & 31;
            float s2 = bgv;
            #pragma unroll
            for (int w = 0; w < 8; ++w) s2 += lpT[row][w];
            float ev = expf(s2);   // softmax shift-invariant; |logit|~O(5)
            int   rr = recvt3[tm][row];
            if (e0 + row >= eb1) { rr = -1; ev = 0.f; }

            // accumulate: thread owns (col = tid&127, rows rg*8..rg*8+7)
            const int rg  = tid >> 7;
            const int col = tid & 127;
            const bool dothr = (col == 0);
            float run = 0.f, drun = 0.f; int rl_open = -1;
            #pragma unroll
            for (int j = 0; j < 8; ++j) {
                int   src = rg * 8 + j;
                int   rj  = __shfl(rr, src, 64);
                float ej  = __shfl(ev, src, 64);
                int   rl  = (rj >= 0) ? rj - rb0 : -1;
                if (rl != rl_open) {
                    if (rl_open >= 0) {
                        atomicAdd(&agg_lds[rl_open][col], run);
                        if (dothr) atomicAdd(&den_lds[rl_open], drun);
                    }
                    run = 0.f; drun = 0.f; rl_open = rl;
                }
                if (rl >= 0) {
                    run = fmaf(ej, (float)msgt[src][col], run);
                    if (dothr) drun += ej;
                }
            }
            if (rl_open >= 0) {
                atomicAdd(&agg_lds[rl_open][col], run);
                if (dothr) atomicAdd(&den_lds[rl_open], drun);
            }
        }
        p ^= 1;
    }

    // ---- single coalesced flush (also zeroes deg-0 receivers' slots) ----
    __syncthreads();
    for (int idx = tid; idx < RPB * 128; idx += 512) {
        int rl = idx >> 7, c = idx & 127;
        int r = rb0 + rl;
        if (r < rb1) aggr[(size_t)r * 128 + c] = agg_lds[rl][c];
    }
    if (tid < RPB && rb0 + tid < rb1) den[rb0 + tid] = den_lds[tid];
}

// ============================================================================
// Agent MLP. Aggregation already done (aggr/den owned-stores from edge_mlp):
// normalize into XA fragments and run the 2-layer fp16-MFMA MLP.
// ============================================================================
__global__ __launch_bounds__(1024, 4) void agg_agent_mfma(
    const float* __restrict__ aggr, const float* __restrict__ den,
    const f16* __restrict__ F3, const f16* __restrict__ F4,
    const float* __restrict__ bh1, const float* __restrict__ bh2,
    const float* __restrict__ Wout, const float* __restrict__ bout,
    float* __restrict__ out)
{
    __shared__ __align__(16) f16 XA[8][64][8];     // 8 KB
    __shared__ __align__(16) f16 HB2[16][64][8];   // 16 KB
    __shared__ float lpart[16][32];

    const int tid  = threadIdx.x;
    const int wv   = tid >> 6;
    const int lane = tid & 63;
    const int q    = lane >> 4;
    const int li   = lane & 15;
    const int a0i  = blockIdx.x * 32;

    // ---- normalize aggr into XA fragment layout ----
    {
        int g = tid >> 5, c = tid & 31;   // receiver a0i+g, cols [c*4, c*4+4)
        int r = a0i + g;
        float4 a = make_float4(0.f, 0.f, 0.f, 0.f);
        float d = 1e-9f;
        if (r < N_AGENTS) {
            a = *(const float4*)&aggr[(size_t)r * 128 + c * 4];
            d += den[r];
        }
        float inv = 1.0f / d;
        int k0   = c * 4;
        int slot = (g >> 4) * 4 + (k0 >> 5);
        int ln   = (g & 15) + 16 * ((k0 & 31) >> 3);
        int j0   = k0 & 7;
        f16x4 h;
        h.x = (f16)(a.x * inv); h.y = (f16)(a.y * inv);
        h.z = (f16)(a.z * inv); h.w = (f16)(a.w * inv);
        *(f16x4*)&XA[slot][ln][j0] = h;
    }
    __syncthreads();

    // ---- weight fragments + layer 1 ----
    f16x8 wh1[4], wh2[8];
    #pragma unroll
    for (int ks = 0; ks < 4; ++ks)
        wh1[ks] = *(const f16x8*)(F3 + (((size_t)(ks * 16 + wv)) * 64 + lane) * 8);
    #pragma unroll
    for (int ks = 0; ks < 8; ++ks)
        wh2[ks] = *(const f16x8*)(F4 + (((size_t)(ks * 16 + wv)) * 64 + lane) * 8);

    f32x4 acc[2] = {};
    #pragma unroll
    for (int ks = 0; ks < 4; ++ks)
        #pragma unroll
        for (int eh = 0; eh < 2; ++eh) {
            f16x8 xh = *(const f16x8*)XA[eh * 4 + ks][lane];
            acc[eh] = __builtin_amdgcn_mfma_f32_16x16x32_f16(wh1[ks], xh, acc[eh], 0, 0, 0);
        }
    {
        const float4 b1v = ((const float4*)bh1)[wv * 4 + q];
        #pragma unroll
        for (int eh = 0; eh < 2; ++eh) {
            f16x4 hv;
            hv.x = (f16)fmaxf(acc[eh][0] + b1v.x, 0.f);
            hv.y = (f16)fmaxf(acc[eh][1] + b1v.y, 0.f);
            hv.z = (f16)fmaxf(acc[eh][2] + b1v.z, 0.f);
            hv.w = (f16)fmaxf(acc[eh][3] + b1v.w, 0.f);
            int l2 = li + 16 * ((wv & 1) * 2 + (q >> 1));
            int j0 = (q & 1) * 4;
            *(f16x4*)&HB2[eh * 8 + (wv >> 1)][l2][j0] = hv;
        }
    }
    __syncthreads();

    // ---- layer 2 + output partial ----
    f32x4 acc2[2] = {};
    #pragma unroll
    for (int ks2 = 0; ks2 < 8; ++ks2)
        #pragma unroll
        for (int eh = 0; eh < 2; ++eh) {
            f16x8 hh = *(const f16x8*)HB2[eh * 8 + ks2][lane];
            acc2[eh] = __builtin_amdgcn_mfma_f32_16x16x32_f16(wh2[ks2], hh, acc2[eh], 0, 0, 0);
        }
    {
        const float4 b2v = ((const float4*)bh2)[wv * 4 + q];
        const float4 wo4 = ((const float4*)Wout)[wv * 4 + q];
        float pr[2];
        #pragma unroll
        for (int eh = 0; eh < 2; ++eh) {
            float pp = fmaxf(acc2[eh][0] + b2v.x, 0.f) * wo4.x
                     + fmaxf(acc2[eh][1] + b2v.y, 0.f) * wo4.y
                     + fmaxf(acc2[eh][2] + b2v.z, 0.f) * wo4.z
                     + fmaxf(acc2[eh][3] + b2v.w, 0.f) * wo4.w;
            pp += __shfl_xor(pp, 16, 64);
            pp += __shfl_xor(pp, 32, 64);
            pr[eh] = pp;
        }
        if (lane < 16) {
            lpart[wv][li]      = pr[0];
            lpart[wv][16 + li] = pr[1];
        }
    }
    __syncthreads();

    if (tid < 32 && a0i + tid < N_AGENTS) {
        float s = bout[0];
        #pragma unroll
        for (int w = 0; w < 16; ++w) s += lpart[w][tid];
        out[a0i + tid] = tanhf(s);
    }
}

// ============================================================================
extern "C" void kernel_launch(void* const* d_in, const int* in_sizes, int n_in,
                              void* d_out, int out_size, void* d_ws, size_t ws_size,
                              hipStream_t stream)
{
    const float* nf   = (const float*)d_in[0];
    const float* ef   = (const float*)d_in[1];
    const float* W1   = (const float*)d_in[2];
    const float* b1   = (const float*)d_in[3];
    const float* W2   = (const float*)d_in[4];
    const float* b2   = (const float*)d_in[5];
    const float* wg   = (const float*)d_in[6];
    const float* bg   = (const float*)d_in[7];
    const float* Wh1  = (const float*)d_in[8];
    const float* bh1  = (const float*)d_in[9];
    const float* Wh2  = (const float*)d_in[10];
    const float* bh2  = (const float*)d_in[11];
    const float* Wout = (const float*)d_in[12];
    const float* bout = (const float*)d_in[13];
    const int*   send = (const int*)d_in[14];
    const int*   recv = (const int*)d_in[15];

    // workspace: [deg|eidb|sendb|recvb] zeroed (tail slots of the last padded
    // tile must gather row 0). aggr/den NOT zeroed: edge_mlp's flush writes
    // every owned slot (including deg-0 receivers).
    char* ws = (char*)d_ws;
    int* deg    = (int*)ws;            ws += (size_t)N_AGENTS * 4;
    int* eidb   = (int*)ws;            ws += (size_t)EPAD * 4;
    int* sendb  = (int*)ws;            ws += (size_t)EPAD * 4;
    int* recvb  = (int*)ws;            ws += (size_t)EPAD * 4;
    size_t zero_bytes = (size_t)(ws - (char*)d_ws);
    float* den  = (float*)ws;          ws += (size_t)N_AGENTS * 4;
    float* aggr = (float*)ws;          ws += (size_t)N_AGENTS * 128 * 4;
    int* rankb  = (int*)ws;            ws += (size_t)N_EDGES * 4;
    int* off    = (int*)ws;            ws += (size_t)(N_AGENTS + 8) * 4;
    f16* nf16   = (f16*)ws;            ws += (size_t)N_NODES * ND * 2;
    f16* F1     = (f16*)ws;            ws += (size_t)160 * 256 * 2;
    f16* F2     = (f16*)ws;            ws += (size_t)256 * 128 * 2;
    f16* F3     = (f16*)ws;            ws += (size_t)128 * 256 * 2;
    f16* F4     = (f16*)ws;            ws += (size_t)256 * 256 * 2;

    hipMemsetAsync(d_ws, 0, zero_bytes, stream);

    compact_pack_kernel<<<N_EDGES / 256 + 84, 256, 0, stream>>>(
        recv, nf, nf16, rankb, deg, W1, W2, Wh1, Wh2, F1, F2, F3, F4);
    prefix_kernel<<<1, 1024, 0, stream>>>(deg, off);
    scatter_kernel<<<N_EDGES / 256, 256, 0, stream>>>(
        recv, send, rankb, off, eidb, sendb, recvb);
    edge_mlp_mfma<<<(N_AGENTS + RPB - 1) / RPB, 512, 0, stream>>>(
        nf16, ef, F1, F2, b1, b2, wg, bg, sendb, recvb, eidb, off, aggr, den);
    agg_agent_mfma<<<(N_AGENTS + 31) / 32, 1024, 0, stream>>>(
        aggr, den, F3, F4, bh1, bh2, Wout, bout, (float*)d_out);
}

// Round 14
// 364.616 us; speedup vs baseline: 1.2945x; 1.2945x over previous
//
#include <hip/hip_runtime.h>
#include <hip/hip_bf16.h>

#define N_NODES  50000
#define N_EDGES  800000
#define ND       64
#define ED       32
#define MSGD     128
#define HIDD     256
#define N_AGENTS 25000
#define EPAD     800064   // N_EDGES + 64 (tile padding)

typedef _Float16 f16;
typedef __attribute__((ext_vector_type(4))) _Float16 f16x4;
typedef __attribute__((ext_vector_type(8))) _Float16 f16x8;
typedef __attribute__((ext_vector_type(4))) float f32x4;
typedef unsigned short u16;
typedef unsigned int   u32;
typedef unsigned long long u64;

// ============================================================================
// compact + nf->f16 + weight pack fused.
// Blocks [0, 3125): compact path. Blocks [3125, 3209): pack path.
// ============================================================================
__global__ __launch_bounds__(256) void compact_pack_kernel(
    const int* __restrict__ recv, const float* __restrict__ nf,
    f16* __restrict__ nf16, int* __restrict__ rankb, int* __restrict__ deg,
    const float* __restrict__ W1, const float* __restrict__ W2,
    const float* __restrict__ Wh1, const float* __restrict__ Wh2,
    f16* __restrict__ F1, f16* __restrict__ F2,
    f16* __restrict__ F3, f16* __restrict__ F4)
{
    int b = blockIdx.x;
    if (b >= N_EDGES / 256) {
        // frag for 16x16x32: lane l, elem j <-> W[k=ks*32+(l>>4)*8+j][n=nt*16+(l&15)]
        int tid  = (b - N_EDGES / 256) * 256 + threadIdx.x;
        int grp  = tid >> 6, lane = tid & 63;
        const float* W; f16* D; int NT, stride, gl;
        if      (grp < 80)  { W = W1;  D = F1; NT = 16; stride = 256; gl = grp; }
        else if (grp < 144) { W = W2;  D = F2; NT = 8;  stride = 128; gl = grp - 80; }
        else if (grp < 208) { W = Wh1; D = F3; NT = 16; stride = 256; gl = grp - 144; }
        else if (grp < 336) { W = Wh2; D = F4; NT = 16; stride = 256; gl = grp - 208; }
        else return;
        int ks = gl / NT, nt = gl - ks * NT;
        int n  = nt * 16 + (lane & 15);
        int k0 = ks * 32 + (lane >> 4) * 8;
        f16* dst = D + ((size_t)gl * 64 + lane) * 8;
        #pragma unroll
        for (int j = 0; j < 8; ++j)
            dst[j] = (f16)W[(size_t)(k0 + j) * stride + n];
        return;
    }
    int i = b * 256 + threadIdx.x;
    {   // nf -> f16 (coalesced float4 read, f16x4 write)
        float4 v = ((const float4*)nf)[i];
        f16x4 h;
        h.x = (f16)v.x; h.y = (f16)v.y; h.z = (f16)v.z; h.w = (f16)v.w;
        ((f16x4*)nf16)[i] = h;
    }
    int r = recv[i];
    if (r < N_AGENTS)
        rankb[i] = atomicAdd(&deg[r], 1);   // 25k addresses, pipelined (R14)
}

// ============================================================================
// prefix, two-kernel parallel form (R21). Old single-block version did 25
// STRIDED global loads/thread (uncoalesced) with the whole GPU idle.
// part: 25 blocks, coalesced 1000-wide sums. scan: 25 blocks, LDS scan.
// ============================================================================
__global__ __launch_bounds__(1024) void prefix_part(
    const int* __restrict__ deg, int* __restrict__ bsum)
{
    __shared__ int red[16];
    int b = blockIdx.x, t = threadIdx.x;
    int v = (t < 1000) ? deg[b * 1000 + t] : 0;
    #pragma unroll
    for (int k = 1; k <= 32; k <<= 1) v += __shfl_xor(v, k, 64);
    if ((t & 63) == 0) red[t >> 6] = v;
    __syncthreads();
    if (t == 0) {
        int s = 0;
        #pragma unroll
        for (int w = 0; w < 16; ++w) s += red[w];
        bsum[b] = s;
    }
}

__global__ __launch_bounds__(1024) void prefix_scan(
    const int* __restrict__ deg, const int* __restrict__ bsum,
    int* __restrict__ off)
{
    __shared__ int part[1024];
    __shared__ int basesh;
    int b = blockIdx.x, t = threadIdx.x;
    if (t == 0) {
        int s = 0;
        for (int j = 0; j < b; ++j) s += bsum[j];
        basesh = s;
    }
    int v = (t < 1000) ? deg[b * 1000 + t] : 0;
    part[t] = v;
    __syncthreads();
    for (int d = 1; d < 1024; d <<= 1) {
        int u = (t >= d) ? part[t - d] : 0;
        __syncthreads();
        part[t] += u;
        __syncthreads();
    }
    int incl = part[t];
    int base = basesh;
    if (t < 1000) off[b * 1000 + t] = base + incl - v;
    if (b == 24 && t == 999) off[N_AGENTS] = base + incl;
}

// ============================================================================
// scatter (no atomics): pos = off[recv] + rankb. R21: ONE int4 {eid,send,
// recv,0} store per kept edge (was 3 scattered 4B stores -> 3 write-allocate
// lines each; now 1). Pad tail of idx4 is zeroed -> gathers hit row 0.
// ============================================================================
__global__ __launch_bounds__(256) void scatter_kernel(
    const int* __restrict__ recv, const int* __restrict__ send,
    const int* __restrict__ rankb, const int* __restrict__ off,
    int4* __restrict__ idx4)
{
    int i = blockIdx.x * 256 + threadIdx.x;
    int r = recv[i];
    if (r < N_AGENTS) {
        int pos = off[r] + rankb[i];
        idx4[pos] = make_int4(i, send[i], r, 0);
    }
}

// ============================================================================
// Edge MLP — EXACT R14 structure (147 us, FETCH 71 MB, total 416 — the
// verified best). Fused-aggregation program (R17-R20) abandoned: 4 variants,
// all worse in total (tail cost in-kernel > round-trip cost out-of-kernel).
// HARD RULE (R8/R9/R15/R20): staging = combined load+ds_write ROLLED loop +
// __syncthreads; do NOT add branches/stores to it; grid 512 (R12/R16).
// R21 delta: index source is the combined idx4 array (comp 0=eid,1=send,
// 2=recv) — same broadcast loads, 3 comps share one cache line.
// ============================================================================
__global__ __launch_bounds__(512, 4) void edge_mlp_mfma(
    const f16* __restrict__ nf16, const float* __restrict__ ef,
    const f16* __restrict__ F1, const f16* __restrict__ F2,
    const float* __restrict__ b1, const float* __restrict__ b2,
    const float* __restrict__ wg, const float* __restrict__ bg,
    const int* __restrict__ idx4i, const int* __restrict__ cnt,
    f16* __restrict__ msg_out, float* __restrict__ evals)
{
    __shared__ __align__(16) f16 XF[2][10][64][8];  // 20 KB (double buffer)
    __shared__ __align__(16) f16 HB[16][64][8];     // 16 KB
    __shared__ __align__(16) f16 msgt[32][136];     // 8.5 KB
    __shared__ float lpart[8][32];

    const int tid  = threadIdx.x;
    const int wv   = tid >> 6;
    const int lane = tid & 63;
    const int q    = lane >> 4;
    const int li   = lane & 15;
    const int cntv   = cnt[0];
    const int ntiles = (cntv + 31) >> 5;

    // XCD-chunked tile assignment:
    const int xcd   = blockIdx.x & 7;
    const int bslot = blockIdx.x >> 3;
    const int tstep = gridDim.x >> 3;          // blocks per XCD
    const int T8    = (ntiles + 7) >> 3;
    const int tend  = min((xcd + 1) * T8, ntiles);
    const int t0    = xcd * T8 + bslot;

    // stationary weight fragments: W1 2 col-tiles + W2 1 col-tile per wave
    f16x8 w1[2][5], w2[8];
    #pragma unroll
    for (int ntl = 0; ntl < 2; ++ntl)
        #pragma unroll
        for (int ks = 0; ks < 5; ++ks)
            w1[ntl][ks] = *(const f16x8*)(F1 + (((size_t)(ks * 16 + 2 * wv + ntl)) * 64 + lane) * 8);
    #pragma unroll
    for (int ks = 0; ks < 8; ++ks)
        w2[ks] = *(const f16x8*)(F2 + (((size_t)(ks * 8 + wv)) * 64 + lane) * 8);

    const float4 ba  = *(const float4*)&b1[wv * 32 + q * 4];
    const float4 bb  = *(const float4*)&b1[wv * 32 + 16 + q * 4];
    const float4 bc  = *(const float4*)&b2[wv * 16 + q * 4];
    const float4 wg4 = *(const float4*)&wg[wv * 16 + q * 4];
    const float  bgv = bg[0];

    // ---- prologue: stage first tile into XF[0] (R10 idiom — rolled) ----
    if (t0 < tend) {
        const int e0p = t0 * 32;
        f16 (*XFd)[64][8] = XF[0];
        for (int idx = tid; idx < 768; idx += 512) {
            int e = idx / 24, g = idx - e * 24;
            int cp = e0p + e;
            if (g < 16) {
                int node = idx4i[cp * 4 + ((g < 8) ? 1 : 2)];
                f16x8 h = *(const f16x8*)(nf16 + (size_t)node * 64 + (g & 7) * 8);
                int slt = (e >> 4) * 5 + (g >> 2);
                int ln  = (e & 15) + 16 * (g & 3);
                *(f16x8*)&XFd[slt][ln][0] = h;
            } else {
                int eid = idx4i[cp * 4];
                float4 v = ((const float4*)ef)[(size_t)eid * 8 + (g - 16)];
                int k0  = 128 + (g - 16) * 4;
                int slt = (e >> 4) * 5 + 4;
                int ln  = (e & 15) + 16 * ((k0 & 31) >> 3);
                int j0  = k0 & 7;
                f16x4 h;
                h.x = (f16)v.x; h.y = (f16)v.y; h.z = (f16)v.z; h.w = (f16)v.w;
                *(f16x4*)&XFd[slt][ln][j0] = h;
            }
        }
    }
    __syncthreads();

    int p = 0;
    for (int t = t0; t < tend; t += tstep) {
        const int e0 = t * 32;
        const int tn = t + tstep;

        // ---- stage NEXT tile into XF[p^1] — no barrier before layer1 ----
        if (tn < tend) {
            const int e0n = tn * 32;
            f16 (*XFd)[64][8] = XF[p ^ 1];
            for (int idx = tid; idx < 768; idx += 512) {
                int e = idx / 24, g = idx - e * 24;
                int cp = e0n + e;
                if (g < 16) {
                    int node = idx4i[cp * 4 + ((g < 8) ? 1 : 2)];
                    f16x8 h = *(const f16x8*)(nf16 + (size_t)node * 64 + (g & 7) * 8);
                    int slt = (e >> 4) * 5 + (g >> 2);
                    int ln  = (e & 15) + 16 * (g & 3);
                    *(f16x8*)&XFd[slt][ln][0] = h;
                } else {
                    int eid = idx4i[cp * 4];
                    float4 v = ((const float4*)ef)[(size_t)eid * 8 + (g - 16)];
                    int k0  = 128 + (g - 16) * 4;
                    int slt = (e >> 4) * 5 + 4;
                    int ln  = (e & 15) + 16 * ((k0 & 31) >> 3);
                    int j0  = k0 & 7;
                    f16x4 h;
                    h.x = (f16)v.x; h.y = (f16)v.y; h.z = (f16)v.z; h.w = (f16)v.w;
                    *(f16x4*)&XFd[slt][ln][j0] = h;
                }
            }
        }

        // ---- layer 1: h[col][edge] = W1^T x^T (from XF[p]) ----
        f32x4 acc[2][2];   // [eh][ntl]
        acc[0][0] = f32x4{ba.x, ba.y, ba.z, ba.w}; acc[1][0] = acc[0][0];
        acc[0][1] = f32x4{bb.x, bb.y, bb.z, bb.w}; acc[1][1] = acc[0][1];
        #pragma unroll
        for (int ks = 0; ks < 5; ++ks)
            #pragma unroll
            for (int eh = 0; eh < 2; ++eh) {
                f16x8 xh = *(const f16x8*)XF[p][eh * 5 + ks][lane];
                acc[eh][0] = __builtin_amdgcn_mfma_f32_16x16x32_f16(w1[0][ks], xh, acc[eh][0], 0, 0, 0);
                acc[eh][1] = __builtin_amdgcn_mfma_f32_16x16x32_f16(w1[1][ks], xh, acc[eh][1], 0, 0, 0);
            }
        // relu + stash h as layer-2 B frags
        #pragma unroll
        for (int eh = 0; eh < 2; ++eh)
            #pragma unroll
            for (int ntl = 0; ntl < 2; ++ntl) {
                f16x4 hv;
                hv.x = (f16)fmaxf(acc[eh][ntl][0], 0.f);
                hv.y = (f16)fmaxf(acc[eh][ntl][1], 0.f);
                hv.z = (f16)fmaxf(acc[eh][ntl][2], 0.f);
                hv.w = (f16)fmaxf(acc[eh][ntl][3], 0.f);
                int l2 = li + 16 * (2 * ntl + (q >> 1));
                int j0 = (q & 1) * 4;
                *(f16x4*)&HB[eh * 8 + wv][l2][j0] = hv;
            }
        __syncthreads();   // B1: HB ready; XF[p^1] staged

        // ---- layer 2: msg[col][edge] = W2^T h^T ----
        f32x4 acc2[2];
        acc2[0] = f32x4{bc.x, bc.y, bc.z, bc.w}; acc2[1] = acc2[0];
        #pragma unroll
        for (int ks2 = 0; ks2 < 8; ++ks2)
            #pragma unroll
            for (int eh = 0; eh < 2; ++eh) {
                f16x8 hh = *(const f16x8*)HB[eh * 8 + ks2][lane];
                acc2[eh] = __builtin_amdgcn_mfma_f32_16x16x32_f16(w2[ks2], hh, acc2[eh], 0, 0, 0);
            }
        // relu + gate partial + msg stash
        {
            float pr[2];
            #pragma unroll
            for (int eh = 0; eh < 2; ++eh) {
                float v0 = fmaxf(acc2[eh][0], 0.f);
                float v1 = fmaxf(acc2[eh][1], 0.f);
                float v2 = fmaxf(acc2[eh][2], 0.f);
                float v3 = fmaxf(acc2[eh][3], 0.f);
                f16x4 mm;
                mm.x = (f16)v0; mm.y = (f16)v1; mm.z = (f16)v2; mm.w = (f16)v3;
                *(f16x4*)&msgt[eh * 16 + li][wv * 16 + q * 4] = mm;
                float pp = v0 * wg4.x + v1 * wg4.y + v2 * wg4.z + v3 * wg4.w;
                pp += __shfl_xor(pp, 16, 64);
                pp += __shfl_xor(pp, 32, 64);
                pr[eh] = pp;
            }
            if (lane < 16) {
                lpart[wv][li]      = pr[0];
                lpart[wv][16 + li] = pr[1];
            }
        }
        __syncthreads();   // B2: msgt/lpart ready

        // ---- writeback: coalesced msg rows + evals = exp(logit) ----
        {
            int row = tid >> 4, cg = tid & 15;
            *(uint4*)(msg_out + (size_t)(e0 + row) * 128 + cg * 8) =
                *(const uint4*)&msgt[row][cg * 8];
        }
        if (tid < 32) {
            float s2 = bgv;
            #pragma unroll
            for (int w = 0; w < 8; ++w) s2 += lpart[w][tid];
            evals[e0 + tid] = expf(s2);   // softmax shift-invariant; |logit|~O(5)
        }
        p ^= 1;
    }
}

// ============================================================================
// Fused CSR softmax-aggregation + agent MLP (R14 verified form). 1024 thr,
// 32 receivers/block; 32 threads/receiver, 4 cols each, 4-way pipelined.
// ============================================================================
__global__ __launch_bounds__(1024, 4) void agg_agent_mfma(
    const int* __restrict__ off, const float* __restrict__ evals,
    const f16* __restrict__ msg,
    const f16* __restrict__ F3, const f16* __restrict__ F4,
    const float* __restrict__ bh1, const float* __restrict__ bh2,
    const float* __restrict__ Wout, const float* __restrict__ bout,
    float* __restrict__ out)
{
    __shared__ __align__(16) f16 XA[8][64][8];     // 8 KB
    __shared__ __align__(16) f16 HB2[16][64][8];   // 16 KB
    __shared__ float lpart[16][32];

    const int tid  = threadIdx.x;
    const int wv   = tid >> 6;
    const int lane = tid & 63;
    const int q    = lane >> 4;
    const int li   = lane & 15;
    const int a0i  = blockIdx.x * 32;

    // ---- aggregation straight into XA fragment layout ----
    {
        int g = tid >> 5, c = tid & 31;   // receiver a0i+g, cols [c*4, c*4+4)
        int r = a0i + g;
        float den = 1e-9f;
        float4 acc = make_float4(0.f, 0.f, 0.f, 0.f);
        if (r < N_AGENTS) {
            int beg = off[r], end = off[r + 1];
            const u64* mp = (const u64*)(msg + (size_t)beg * 128) + c;
            int pp = beg;
            for (; pp + 3 < end; pp += 4, mp += 128) {
                float e0 = evals[pp], e1 = evals[pp + 1];
                float e2 = evals[pp + 2], e3 = evals[pp + 3];
                u64 u0 = mp[0], u1 = mp[32], u2 = mp[64], u3 = mp[96];
                den += (e0 + e1) + (e2 + e3);
                union { u64 u; f16 h[4]; } c0, c1, c2, c3;
                c0.u = u0; c1.u = u1; c2.u = u2; c3.u = u3;
                acc.x = fmaf(e3, (float)c3.h[0], fmaf(e2, (float)c2.h[0],
                        fmaf(e1, (float)c1.h[0], fmaf(e0, (float)c0.h[0], acc.x))));
                acc.y = fmaf(e3, (float)c3.h[1], fmaf(e2, (float)c2.h[1],
                        fmaf(e1, (float)c1.h[1], fmaf(e0, (float)c0.h[1], acc.y))));
                acc.z = fmaf(e3, (float)c3.h[2], fmaf(e2, (float)c2.h[2],
                        fmaf(e1, (float)c1.h[2], fmaf(e0, (float)c0.h[2], acc.z))));
                acc.w = fmaf(e3, (float)c3.h[3], fmaf(e2, (float)c2.h[3],
                        fmaf(e1, (float)c1.h[3], fmaf(e0, (float)c0.h[3], acc.w))));
            }
            for (; pp < end; ++pp, mp += 32) {
                float e = evals[pp];
                den += e;
                union { u64 u; f16 h[4]; } cv; cv.u = *mp;
                acc.x = fmaf(e, (float)cv.h[0], acc.x);
                acc.y = fmaf(e, (float)cv.h[1], acc.y);
                acc.z = fmaf(e, (float)cv.h[2], acc.z);
                acc.w = fmaf(e, (float)cv.h[3], acc.w);
            }
        }
        float inv = 1.0f / den;
        int k0   = c * 4;
        int slot = (g >> 4) * 4 + (k0 >> 5);
        int ln   = (g & 15) + 16 * ((k0 & 31) >> 3);
        int j0   = k0 & 7;
        f16x4 h;
        h.x = (f16)(acc.x * inv); h.y = (f16)(acc.y * inv);
        h.z = (f16)(acc.z * inv); h.w = (f16)(acc.w * inv);
        *(f16x4*)&XA[slot][ln][j0] = h;
    }
    __syncthreads();

    // ---- weight fragments + layer 1 ----
    f16x8 wh1[4], wh2[8];
    #pragma unroll
    for (int ks = 0; ks < 4; ++ks)
        wh1[ks] = *(const f16x8*)(F3 + (((size_t)(ks * 16 + wv)) * 64 + lane) * 8);
    #pragma unroll
    for (int ks = 0; ks < 8; ++ks)
        wh2[ks] = *(const f16x8*)(F4 + (((size_t)(ks * 16 + wv)) * 64 + lane) * 8);

    f32x4 acc[2] = {};
    #pragma unroll
    for (int ks = 0; ks < 4; ++ks)
        #pragma unroll
        for (int eh = 0; eh < 2; ++eh) {
            f16x8 xh = *(const f16x8*)XA[eh * 4 + ks][lane];
            acc[eh] = __builtin_amdgcn_mfma_f32_16x16x32_f16(wh1[ks], xh, acc[eh], 0, 0, 0);
        }
    {
        const float4 b1v = ((const float4*)bh1)[wv * 4 + q];
        #pragma unroll
        for (int eh = 0; eh < 2; ++eh) {
            f16x4 hv;
            hv.x = (f16)fmaxf(acc[eh][0] + b1v.x, 0.f);
            hv.y = (f16)fmaxf(acc[eh][1] + b1v.y, 0.f);
            hv.z = (f16)fmaxf(acc[eh][2] + b1v.z, 0.f);
            hv.w = (f16)fmaxf(acc[eh][3] + b1v.w, 0.f);
            int l2 = li + 16 * ((wv & 1) * 2 + (q >> 1));
            int j0 = (q & 1) * 4;
            *(f16x4*)&HB2[eh * 8 + (wv >> 1)][l2][j0] = hv;
        }
    }
    __syncthreads();

    // ---- layer 2 + output partial ----
    f32x4 acc2[2] = {};
    #pragma unroll
    for (int ks2 = 0; ks2 < 8; ++ks2)
        #pragma unroll
        for (int eh = 0; eh < 2; ++eh) {
            f16x8 hh = *(const f16x8*)HB2[eh * 8 + ks2][lane];
            acc2[eh] = __builtin_amdgcn_mfma_f32_16x16x32_f16(wh2[ks2], hh, acc2[eh], 0, 0, 0);
        }
    {
        const float4 b2v = ((const float4*)bh2)[wv * 4 + q];
        const float4 wo4 = ((const float4*)Wout)[wv * 4 + q];
        float pr[2];
        #pragma unroll
        for (int eh = 0; eh < 2; ++eh) {
            float pp = fmaxf(acc2[eh][0] + b2v.x, 0.f) * wo4.x
                     + fmaxf(acc2[eh][1] + b2v.y, 0.f) * wo4.y
                     + fmaxf(acc2[eh][2] + b2v.z, 0.f) * wo4.z
                     + fmaxf(acc2[eh][3] + b2v.w, 0.f) * wo4.w;
            pp += __shfl_xor(pp, 16, 64);
            pp += __shfl_xor(pp, 32, 64);
            pr[eh] = pp;
        }
        if (lane < 16) {
            lpart[wv][li]      = pr[0];
            lpart[wv][16 + li] = pr[1];
        }
    }
    __syncthreads();

    if (tid < 32 && a0i + tid < N_AGENTS) {
        float s = bout[0];
        #pragma unroll
        for (int w = 0; w < 16; ++w) s += lpart[w][tid];
        out[a0i + tid] = tanhf(s);
    }
}

// ============================================================================
extern "C" void kernel_launch(void* const* d_in, const int* in_sizes, int n_in,
                              void* d_out, int out_size, void* d_ws, size_t ws_size,
                              hipStream_t stream)
{
    const float* nf   = (const float*)d_in[0];
    const float* ef   = (const float*)d_in[1];
    const float* W1   = (const float*)d_in[2];
    const float* b1   = (const float*)d_in[3];
    const float* W2   = (const float*)d_in[4];
    const float* b2   = (const float*)d_in[5];
    const float* wg   = (const float*)d_in[6];
    const float* bg   = (const float*)d_in[7];
    const float* Wh1  = (const float*)d_in[8];
    const float* bh1  = (const float*)d_in[9];
    const float* Wh2  = (const float*)d_in[10];
    const float* bh2  = (const float*)d_in[11];
    const float* Wout = (const float*)d_in[12];
    const float* bout = (const float*)d_in[13];
    const int*   send = (const int*)d_in[14];
    const int*   recv = (const int*)d_in[15];

    // workspace: [deg|idx4] zeroed (tail slots of the last padded tile must
    // gather row 0), then the rest
    char* ws = (char*)d_ws;
    int*  deg   = (int*)ws;            ws += (size_t)N_AGENTS * 4;
    int4* idx4  = (int4*)ws;           ws += (size_t)EPAD * 16;
    size_t zero_bytes = (size_t)(ws - (char*)d_ws);
    int* rankb  = (int*)ws;            ws += (size_t)N_EDGES * 4;
    int* bsum   = (int*)ws;            ws += 32 * 4;
    int* off    = (int*)ws;            ws += (size_t)(N_AGENTS + 8) * 4;
    float* evals = (float*)ws;         ws += (size_t)EPAD * 4;
    f16* nf16   = (f16*)ws;            ws += (size_t)N_NODES * ND * 2;
    f16* F1     = (f16*)ws;            ws += (size_t)160 * 256 * 2;
    f16* F2     = (f16*)ws;            ws += (size_t)256 * 128 * 2;
    f16* F3     = (f16*)ws;            ws += (size_t)128 * 256 * 2;
    f16* F4     = (f16*)ws;            ws += (size_t)256 * 256 * 2;
    f16* msg    = (f16*)ws;

    hipMemsetAsync(d_ws, 0, zero_bytes, stream);

    compact_pack_kernel<<<N_EDGES / 256 + 84, 256, 0, stream>>>(
        recv, nf, nf16, rankb, deg, W1, W2, Wh1, Wh2, F1, F2, F3, F4);
    prefix_part<<<25, 1024, 0, stream>>>(deg, bsum);
    prefix_scan<<<25, 1024, 0, stream>>>(deg, bsum, off);
    scatter_kernel<<<N_EDGES / 256, 256, 0, stream>>>(
        recv, send, rankb, off, idx4);
    edge_mlp_mfma<<<512, 512, 0, stream>>>(
        nf16, ef, F1, F2, b1, b2, wg, bg, (const int*)idx4, off + N_AGENTS,
        msg, evals);
    agg_agent_mfma<<<(N_AGENTS + 31) / 32, 1024, 0, stream>>>(
        off, evals, msg, F3, F4, bh1, bh2, Wout, bout, (float*)d_out);
}

// Round 15
// 352.888 us; speedup vs baseline: 1.3375x; 1.0332x over previous
//
#include <hip/hip_runtime.h>
#include <hip/hip_bf16.h>

#define N_NODES  50000
#define N_EDGES  800000
#define ND       64
#define ED       32
#define MSGD     128
#define HIDD     256
#define N_AGENTS 25000
#define EPAD     800064   // N_EDGES + 64 (tile padding)

typedef _Float16 f16;
typedef __attribute__((ext_vector_type(4))) _Float16 f16x4;
typedef __attribute__((ext_vector_type(8))) _Float16 f16x8;
typedef __attribute__((ext_vector_type(4))) float f32x4;
typedef unsigned short u16;
typedef unsigned int   u32;
typedef unsigned long long u64;

// ============================================================================
// compact + nf->f16 + weight pack fused.
// Blocks [0, 3125): compact path. Blocks [3125, 3209): pack path.
// ============================================================================
__global__ __launch_bounds__(256) void compact_pack_kernel(
    const int* __restrict__ recv, const float* __restrict__ nf,
    f16* __restrict__ nf16, int* __restrict__ rankb, int* __restrict__ deg,
    const float* __restrict__ W1, const float* __restrict__ W2,
    const float* __restrict__ Wh1, const float* __restrict__ Wh2,
    f16* __restrict__ F1, f16* __restrict__ F2,
    f16* __restrict__ F3, f16* __restrict__ F4)
{
    int b = blockIdx.x;
    if (b >= N_EDGES / 256) {
        // frag for 16x16x32: lane l, elem j <-> W[k=ks*32+(l>>4)*8+j][n=nt*16+(l&15)]
        int tid  = (b - N_EDGES / 256) * 256 + threadIdx.x;
        int grp  = tid >> 6, lane = tid & 63;
        const float* W; f16* D; int NT, stride, gl;
        if      (grp < 80)  { W = W1;  D = F1; NT = 16; stride = 256; gl = grp; }
        else if (grp < 144) { W = W2;  D = F2; NT = 8;  stride = 128; gl = grp - 80; }
        else if (grp < 208) { W = Wh1; D = F3; NT = 16; stride = 256; gl = grp - 144; }
        else if (grp < 336) { W = Wh2; D = F4; NT = 16; stride = 256; gl = grp - 208; }
        else return;
        int ks = gl / NT, nt = gl - ks * NT;
        int n  = nt * 16 + (lane & 15);
        int k0 = ks * 32 + (lane >> 4) * 8;
        f16* dst = D + ((size_t)gl * 64 + lane) * 8;
        #pragma unroll
        for (int j = 0; j < 8; ++j)
            dst[j] = (f16)W[(size_t)(k0 + j) * stride + n];
        return;
    }
    int i = b * 256 + threadIdx.x;
    {   // nf -> f16 (coalesced float4 read, f16x4 write)
        float4 v = ((const float4*)nf)[i];
        f16x4 h;
        h.x = (f16)v.x; h.y = (f16)v.y; h.z = (f16)v.z; h.w = (f16)v.w;
        ((f16x4*)nf16)[i] = h;
    }
    int r = recv[i];
    if (r < N_AGENTS)
        rankb[i] = atomicAdd(&deg[r], 1);   // 25k addresses, pipelined (R14)
}

// ============================================================================
// prefix, two-kernel parallel form (R21, verified).
// ============================================================================
__global__ __launch_bounds__(1024) void prefix_part(
    const int* __restrict__ deg, int* __restrict__ bsum)
{
    __shared__ int red[16];
    int b = blockIdx.x, t = threadIdx.x;
    int v = (t < 1000) ? deg[b * 1000 + t] : 0;
    #pragma unroll
    for (int k = 1; k <= 32; k <<= 1) v += __shfl_xor(v, k, 64);
    if ((t & 63) == 0) red[t >> 6] = v;
    __syncthreads();
    if (t == 0) {
        int s = 0;
        #pragma unroll
        for (int w = 0; w < 16; ++w) s += red[w];
        bsum[b] = s;
    }
}

__global__ __launch_bounds__(1024) void prefix_scan(
    const int* __restrict__ deg, const int* __restrict__ bsum,
    int* __restrict__ off)
{
    __shared__ int part[1024];
    __shared__ int basesh;
    int b = blockIdx.x, t = threadIdx.x;
    if (t == 0) {
        int s = 0;
        for (int j = 0; j < b; ++j) s += bsum[j];
        basesh = s;
    }
    int v = (t < 1000) ? deg[b * 1000 + t] : 0;
    part[t] = v;
    __syncthreads();
    for (int d = 1; d < 1024; d <<= 1) {
        int u = (t >= d) ? part[t - d] : 0;
        __syncthreads();
        part[t] += u;
        __syncthreads();
    }
    int incl = part[t];
    int base = basesh;
    if (t < 1000) off[b * 1000 + t] = base + incl - v;
    if (b == 24 && t == 999) off[N_AGENTS] = base + incl;
}

// ============================================================================
// scatter: pos = off[recv] + rankb; one int4 {eid,send,recv,0} per kept edge
// (R21, verified). R22: optionally ALSO writes efc[pos] = f16(ef[i]) — a
// CSR-ordered f16 copy of edge feats so edge_mlp's ef reads become
// SEQUENTIAL (no eid gather). efc==NULL when workspace too small (fallback).
// ============================================================================
__global__ __launch_bounds__(256) void scatter_kernel(
    const int* __restrict__ recv, const int* __restrict__ send,
    const int* __restrict__ rankb, const int* __restrict__ off,
    int4* __restrict__ idx4, const float* __restrict__ ef,
    f16* __restrict__ efc)
{
    int i = blockIdx.x * 256 + threadIdx.x;
    int r = recv[i];
    if (r < N_AGENTS) {
        int pos = off[r] + rankb[i];
        idx4[pos] = make_int4(i, send[i], r, 0);
        if (efc) {
            f16* dst = efc + (size_t)pos * 32;
            #pragma unroll
            for (int k = 0; k < 8; ++k) {
                float4 v = ((const float4*)ef)[(size_t)i * 8 + k];
                f16x4 h;
                h.x = (f16)v.x; h.y = (f16)v.y; h.z = (f16)v.z; h.w = (f16)v.w;
                *(f16x4*)(dst + k * 4) = h;
            }
        }
    }
}

// ============================================================================
// Edge MLP — R21 verified core (142 us, FETCH 69 MB, total 365).
// HARD RULE (R8/R9/R15/R20): staging = combined load+ds_write ROLLED loop +
// __syncthreads; no extra branches/stores inside it; grid 512.
// R22: when efc != NULL, ef slots read the CSR-ordered f16 copy SEQUENTIALLY
// (f16x8, no eid indirection): 640 lane-loads/tile (was 768), and the random
// 128B f32 ef gather (L3-thrashing, ~900cy) disappears. Geometry-only change
// (same class as R13's 40->24, which was clean). Fallback path is the R21
// loop verbatim.
// ============================================================================
__global__ __launch_bounds__(512, 4) void edge_mlp_mfma(
    const f16* __restrict__ nf16, const float* __restrict__ ef,
    const f16* __restrict__ efc,
    const f16* __restrict__ F1, const f16* __restrict__ F2,
    const float* __restrict__ b1, const float* __restrict__ b2,
    const float* __restrict__ wg, const float* __restrict__ bg,
    const int* __restrict__ idx4i, const int* __restrict__ cnt,
    f16* __restrict__ msg_out, float* __restrict__ evals)
{
    __shared__ __align__(16) f16 XF[2][10][64][8];  // 20 KB (double buffer)
    __shared__ __align__(16) f16 HB[16][64][8];     // 16 KB
    __shared__ __align__(16) f16 msgt[32][136];     // 8.5 KB
    __shared__ float lpart[8][32];

    const int tid  = threadIdx.x;
    const int wv   = tid >> 6;
    const int lane = tid & 63;
    const int q    = lane >> 4;
    const int li   = lane & 15;
    const int cntv   = cnt[0];
    const int ntiles = (cntv + 31) >> 5;

    // XCD-chunked tile assignment:
    const int xcd   = blockIdx.x & 7;
    const int bslot = blockIdx.x >> 3;
    const int tstep = gridDim.x >> 3;          // blocks per XCD
    const int T8    = (ntiles + 7) >> 3;
    const int tend  = min((xcd + 1) * T8, ntiles);
    const int t0    = xcd * T8 + bslot;
    const bool use_efc = (efc != nullptr);

    // stationary weight fragments: W1 2 col-tiles + W2 1 col-tile per wave
    f16x8 w1[2][5], w2[8];
    #pragma unroll
    for (int ntl = 0; ntl < 2; ++ntl)
        #pragma unroll
        for (int ks = 0; ks < 5; ++ks)
            w1[ntl][ks] = *(const f16x8*)(F1 + (((size_t)(ks * 16 + 2 * wv + ntl)) * 64 + lane) * 8);
    #pragma unroll
    for (int ks = 0; ks < 8; ++ks)
        w2[ks] = *(const f16x8*)(F2 + (((size_t)(ks * 8 + wv)) * 64 + lane) * 8);

    const float4 ba  = *(const float4*)&b1[wv * 32 + q * 4];
    const float4 bb  = *(const float4*)&b1[wv * 32 + 16 + q * 4];
    const float4 bc  = *(const float4*)&b2[wv * 16 + q * 4];
    const float4 wg4 = *(const float4*)&wg[wv * 16 + q * 4];
    const float  bgv = bg[0];

    // ---- prologue: stage first tile into XF[0] ----
    if (t0 < tend) {
        const int e0p = t0 * 32;
        f16 (*XFd)[64][8] = XF[0];
        if (use_efc) {
            for (int idx = tid; idx < 640; idx += 512) {
                int e = idx / 20, g = idx - e * 20;
                int cp = e0p + e;
                if (g < 16) {
                    int node = idx4i[cp * 4 + ((g < 8) ? 1 : 2)];
                    f16x8 h = *(const f16x8*)(nf16 + (size_t)node * 64 + (g & 7) * 8);
                    int slt = (e >> 4) * 5 + (g >> 2);
                    int ln  = (e & 15) + 16 * (g & 3);
                    *(f16x8*)&XFd[slt][ln][0] = h;
                } else {
                    f16x8 h = *(const f16x8*)(efc + (size_t)cp * 32 + (g - 16) * 8);
                    int k0  = 128 + (g - 16) * 8;
                    int slt = (e >> 4) * 5 + 4;
                    int ln  = (e & 15) + 16 * ((k0 & 31) >> 3);
                    *(f16x8*)&XFd[slt][ln][0] = h;
                }
            }
        } else {
            for (int idx = tid; idx < 768; idx += 512) {
                int e = idx / 24, g = idx - e * 24;
                int cp = e0p + e;
                if (g < 16) {
                    int node = idx4i[cp * 4 + ((g < 8) ? 1 : 2)];
                    f16x8 h = *(const f16x8*)(nf16 + (size_t)node * 64 + (g & 7) * 8);
                    int slt = (e >> 4) * 5 + (g >> 2);
                    int ln  = (e & 15) + 16 * (g & 3);
                    *(f16x8*)&XFd[slt][ln][0] = h;
                } else {
                    int eid = idx4i[cp * 4];
                    float4 v = ((const float4*)ef)[(size_t)eid * 8 + (g - 16)];
                    int k0  = 128 + (g - 16) * 4;
                    int slt = (e >> 4) * 5 + 4;
                    int ln  = (e & 15) + 16 * ((k0 & 31) >> 3);
                    int j0  = k0 & 7;
                    f16x4 h;
                    h.x = (f16)v.x; h.y = (f16)v.y; h.z = (f16)v.z; h.w = (f16)v.w;
                    *(f16x4*)&XFd[slt][ln][j0] = h;
                }
            }
        }
    }
    __syncthreads();

    int p = 0;
    for (int t = t0; t < tend; t += tstep) {
        const int e0 = t * 32;
        const int tn = t + tstep;

        // ---- stage NEXT tile into XF[p^1] — no barrier before layer1 ----
        if (tn < tend) {
            const int e0n = tn * 32;
            f16 (*XFd)[64][8] = XF[p ^ 1];
            if (use_efc) {
                for (int idx = tid; idx < 640; idx += 512) {
                    int e = idx / 20, g = idx - e * 20;
                    int cp = e0n + e;
                    if (g < 16) {
                        int node = idx4i[cp * 4 + ((g < 8) ? 1 : 2)];
                        f16x8 h = *(const f16x8*)(nf16 + (size_t)node * 64 + (g & 7) * 8);
                        int slt = (e >> 4) * 5 + (g >> 2);
                        int ln  = (e & 15) + 16 * (g & 3);
                        *(f16x8*)&XFd[slt][ln][0] = h;
                    } else {
                        f16x8 h = *(const f16x8*)(efc + (size_t)cp * 32 + (g - 16) * 8);
                        int k0  = 128 + (g - 16) * 8;
                        int slt = (e >> 4) * 5 + 4;
                        int ln  = (e & 15) + 16 * ((k0 & 31) >> 3);
                        *(f16x8*)&XFd[slt][ln][0] = h;
                    }
                }
            } else {
                for (int idx = tid; idx < 768; idx += 512) {
                    int e = idx / 24, g = idx - e * 24;
                    int cp = e0n + e;
                    if (g < 16) {
                        int node = idx4i[cp * 4 + ((g < 8) ? 1 : 2)];
                        f16x8 h = *(const f16x8*)(nf16 + (size_t)node * 64 + (g & 7) * 8);
                        int slt = (e >> 4) * 5 + (g >> 2);
                        int ln  = (e & 15) + 16 * (g & 3);
                        *(f16x8*)&XFd[slt][ln][0] = h;
                    } else {
                        int eid = idx4i[cp * 4];
                        float4 v = ((const float4*)ef)[(size_t)eid * 8 + (g - 16)];
                        int k0  = 128 + (g - 16) * 4;
                        int slt = (e >> 4) * 5 + 4;
                        int ln  = (e & 15) + 16 * ((k0 & 31) >> 3);
                        int j0  = k0 & 7;
                        f16x4 h;
                        h.x = (f16)v.x; h.y = (f16)v.y; h.z = (f16)v.z; h.w = (f16)v.w;
                        *(f16x4*)&XFd[slt][ln][j0] = h;
                    }
                }
            }
        }

        // ---- layer 1: h[col][edge] = W1^T x^T (from XF[p]) ----
        f32x4 acc[2][2];   // [eh][ntl]
        acc[0][0] = f32x4{ba.x, ba.y, ba.z, ba.w}; acc[1][0] = acc[0][0];
        acc[0][1] = f32x4{bb.x, bb.y, bb.z, bb.w}; acc[1][1] = acc[0][1];
        #pragma unroll
        for (int ks = 0; ks < 5; ++ks)
            #pragma unroll
            for (int eh = 0; eh < 2; ++eh) {
                f16x8 xh = *(const f16x8*)XF[p][eh * 5 + ks][lane];
                acc[eh][0] = __builtin_amdgcn_mfma_f32_16x16x32_f16(w1[0][ks], xh, acc[eh][0], 0, 0, 0);
                acc[eh][1] = __builtin_amdgcn_mfma_f32_16x16x32_f16(w1[1][ks], xh, acc[eh][1], 0, 0, 0);
            }
        // relu + stash h as layer-2 B frags
        #pragma unroll
        for (int eh = 0; eh < 2; ++eh)
            #pragma unroll
            for (int ntl = 0; ntl < 2; ++ntl) {
                f16x4 hv;
                hv.x = (f16)fmaxf(acc[eh][ntl][0], 0.f);
                hv.y = (f16)fmaxf(acc[eh][ntl][1], 0.f);
                hv.z = (f16)fmaxf(acc[eh][ntl][2], 0.f);
                hv.w = (f16)fmaxf(acc[eh][ntl][3], 0.f);
                int l2 = li + 16 * (2 * ntl + (q >> 1));
                int j0 = (q & 1) * 4;
                *(f16x4*)&HB[eh * 8 + wv][l2][j0] = hv;
            }
        __syncthreads();   // B1: HB ready; XF[p^1] staged

        // ---- layer 2: msg[col][edge] = W2^T h^T ----
        f32x4 acc2[2];
        acc2[0] = f32x4{bc.x, bc.y, bc.z, bc.w}; acc2[1] = acc2[0];
        #pragma unroll
        for (int ks2 = 0; ks2 < 8; ++ks2)
            #pragma unroll
            for (int eh = 0; eh < 2; ++eh) {
                f16x8 hh = *(const f16x8*)HB[eh * 8 + ks2][lane];
                acc2[eh] = __builtin_amdgcn_mfma_f32_16x16x32_f16(w2[ks2], hh, acc2[eh], 0, 0, 0);
            }
        // relu + gate partial + msg stash
        {
            float pr[2];
            #pragma unroll
            for (int eh = 0; eh < 2; ++eh) {
                float v0 = fmaxf(acc2[eh][0], 0.f);
                float v1 = fmaxf(acc2[eh][1], 0.f);
                float v2 = fmaxf(acc2[eh][2], 0.f);
                float v3 = fmaxf(acc2[eh][3], 0.f);
                f16x4 mm;
                mm.x = (f16)v0; mm.y = (f16)v1; mm.z = (f16)v2; mm.w = (f16)v3;
                *(f16x4*)&msgt[eh * 16 + li][wv * 16 + q * 4] = mm;
                float pp = v0 * wg4.x + v1 * wg4.y + v2 * wg4.z + v3 * wg4.w;
                pp += __shfl_xor(pp, 16, 64);
                pp += __shfl_xor(pp, 32, 64);
                pr[eh] = pp;
            }
            if (lane < 16) {
                lpart[wv][li]      = pr[0];
                lpart[wv][16 + li] = pr[1];
            }
        }
        __syncthreads();   // B2: msgt/lpart ready

        // ---- writeback: coalesced msg rows + evals = exp(logit) ----
        {
            int row = tid >> 4, cg = tid & 15;
            *(uint4*)(msg_out + (size_t)(e0 + row) * 128 + cg * 8) =
                *(const uint4*)&msgt[row][cg * 8];
        }
        if (tid < 32) {
            float s2 = bgv;
            #pragma unroll
            for (int w = 0; w < 8; ++w) s2 += lpart[w][tid];
            evals[e0 + tid] = expf(s2);   // softmax shift-invariant; |logit|~O(5)
        }
        p ^= 1;
    }
}

// ============================================================================
// Fused CSR softmax-aggregation + agent MLP (R14/R21 verified form).
// R22: XCD-chunked block mapping mirrors edge_mlp's, so each agg block reads
// the msg range written by the same XCD (its freshest lines L2-resident).
// ============================================================================
__global__ __launch_bounds__(1024, 4) void agg_agent_mfma(
    const int* __restrict__ off, const float* __restrict__ evals,
    const f16* __restrict__ msg,
    const f16* __restrict__ F3, const f16* __restrict__ F4,
    const float* __restrict__ bh1, const float* __restrict__ bh2,
    const float* __restrict__ Wout, const float* __restrict__ bout,
    float* __restrict__ out)
{
    __shared__ __align__(16) f16 XA[8][64][8];     // 8 KB
    __shared__ __align__(16) f16 HB2[16][64][8];   // 16 KB
    __shared__ float lpart[16][32];

    const int tid  = threadIdx.x;
    const int wv   = tid >> 6;
    const int lane = tid & 63;
    const int q    = lane >> 4;
    const int li   = lane & 15;
    // XCD-chunked receiver-block mapping (98 slots/XCD, 784 blocks):
    const int xcd   = blockIdx.x & 7;
    const int bslot = blockIdx.x >> 3;
    const int bidx  = xcd * 98 + bslot;
    if (bidx * 32 >= N_AGENTS) return;     // uniform early-out, pre-barrier
    const int a0i  = bidx * 32;

    // ---- aggregation straight into XA fragment layout ----
    {
        int g = tid >> 5, c = tid & 31;   // receiver a0i+g, cols [c*4, c*4+4)
        int r = a0i + g;
        float den = 1e-9f;
        float4 acc = make_float4(0.f, 0.f, 0.f, 0.f);
        if (r < N_AGENTS) {
            int beg = off[r], end = off[r + 1];
            const u64* mp = (const u64*)(msg + (size_t)beg * 128) + c;
            int pp = beg;
            for (; pp + 3 < end; pp += 4, mp += 128) {
                float e0 = evals[pp], e1 = evals[pp + 1];
                float e2 = evals[pp + 2], e3 = evals[pp + 3];
                u64 u0 = mp[0], u1 = mp[32], u2 = mp[64], u3 = mp[96];
                den += (e0 + e1) + (e2 + e3);
                union { u64 u; f16 h[4]; } c0, c1, c2, c3;
                c0.u = u0; c1.u = u1; c2.u = u2; c3.u = u3;
                acc.x = fmaf(e3, (float)c3.h[0], fmaf(e2, (float)c2.h[0],
                        fmaf(e1, (float)c1.h[0], fmaf(e0, (float)c0.h[0], acc.x))));
                acc.y = fmaf(e3, (float)c3.h[1], fmaf(e2, (float)c2.h[1],
                        fmaf(e1, (float)c1.h[1], fmaf(e0, (float)c0.h[1], acc.y))));
                acc.z = fmaf(e3, (float)c3.h[2], fmaf(e2, (float)c2.h[2],
                        fmaf(e1, (float)c1.h[2], fmaf(e0, (float)c0.h[2], acc.z))));
                acc.w = fmaf(e3, (float)c3.h[3], fmaf(e2, (float)c2.h[3],
                        fmaf(e1, (float)c1.h[3], fmaf(e0, (float)c0.h[3], acc.w))));
            }
            for (; pp < end; ++pp, mp += 32) {
                float e = evals[pp];
                den += e;
                union { u64 u; f16 h[4]; } cv; cv.u = *mp;
                acc.x = fmaf(e, (float)cv.h[0], acc.x);
                acc.y = fmaf(e, (float)cv.h[1], acc.y);
                acc.z = fmaf(e, (float)cv.h[2], acc.z);
                acc.w = fmaf(e, (float)cv.h[3], acc.w);
            }
        }
        float inv = 1.0f / den;
        int k0   = c * 4;
        int slot = (g >> 4) * 4 + (k0 >> 5);
        int ln   = (g & 15) + 16 * ((k0 & 31) >> 3);
        int j0   = k0 & 7;
        f16x4 h;
        h.x = (f16)(acc.x * inv); h.y = (f16)(acc.y * inv);
        h.z = (f16)(acc.z * inv); h.w = (f16)(acc.w * inv);
        *(f16x4*)&XA[slot][ln][j0] = h;
    }
    __syncthreads();

    // ---- weight fragments + layer 1 ----
    f16x8 wh1[4], wh2[8];
    #pragma unroll
    for (int ks = 0; ks < 4; ++ks)
        wh1[ks] = *(const f16x8*)(F3 + (((size_t)(ks * 16 + wv)) * 64 + lane) * 8);
    #pragma unroll
    for (int ks = 0; ks < 8; ++ks)
        wh2[ks] = *(const f16x8*)(F4 + (((size_t)(ks * 16 + wv)) * 64 + lane) * 8);

    f32x4 acc[2] = {};
    #pragma unroll
    for (int ks = 0; ks < 4; ++ks)
        #pragma unroll
        for (int eh = 0; eh < 2; ++eh) {
            f16x8 xh = *(const f16x8*)XA[eh * 4 + ks][lane];
            acc[eh] = __builtin_amdgcn_mfma_f32_16x16x32_f16(wh1[ks], xh, acc[eh], 0, 0, 0);
        }
    {
        const float4 b1v = ((const float4*)bh1)[wv * 4 + q];
        #pragma unroll
        for (int eh = 0; eh < 2; ++eh) {
            f16x4 hv;
            hv.x = (f16)fmaxf(acc[eh][0] + b1v.x, 0.f);
            hv.y = (f16)fmaxf(acc[eh][1] + b1v.y, 0.f);
            hv.z = (f16)fmaxf(acc[eh][2] + b1v.z, 0.f);
            hv.w = (f16)fmaxf(acc[eh][3] + b1v.w, 0.f);
            int l2 = li + 16 * ((wv & 1) * 2 + (q >> 1));
            int j0 = (q & 1) * 4;
            *(f16x4*)&HB2[eh * 8 + (wv >> 1)][l2][j0] = hv;
        }
    }
    __syncthreads();

    // ---- layer 2 + output partial ----
    f32x4 acc2[2] = {};
    #pragma unroll
    for (int ks2 = 0; ks2 < 8; ++ks2)
        #pragma unroll
        for (int eh = 0; eh < 2; ++eh) {
            f16x8 hh = *(const f16x8*)HB2[eh * 8 + ks2][lane];
            acc2[eh] = __builtin_amdgcn_mfma_f32_16x16x32_f16(wh2[ks2], hh, acc2[eh], 0, 0, 0);
        }
    {
        const float4 b2v = ((const float4*)bh2)[wv * 4 + q];
        const float4 wo4 = ((const float4*)Wout)[wv * 4 + q];
        float pr[2];
        #pragma unroll
        for (int eh = 0; eh < 2; ++eh) {
            float pp = fmaxf(acc2[eh][0] + b2v.x, 0.f) * wo4.x
                     + fmaxf(acc2[eh][1] + b2v.y, 0.f) * wo4.y
                     + fmaxf(acc2[eh][2] + b2v.z, 0.f) * wo4.z
                     + fmaxf(acc2[eh][3] + b2v.w, 0.f) * wo4.w;
            pp += __shfl_xor(pp, 16, 64);
            pp += __shfl_xor(pp, 32, 64);
            pr[eh] = pp;
        }
        if (lane < 16) {
            lpart[wv][li]      = pr[0];
            lpart[wv][16 + li] = pr[1];
        }
    }
    __syncthreads();

    if (tid < 32 && a0i + tid < N_AGENTS) {
        float s = bout[0];
        #pragma unroll
        for (int w = 0; w < 16; ++w) s += lpart[w][tid];
        out[a0i + tid] = tanhf(s);
    }
}

// ============================================================================
extern "C" void kernel_launch(void* const* d_in, const int* in_sizes, int n_in,
                              void* d_out, int out_size, void* d_ws, size_t ws_size,
                              hipStream_t stream)
{
    const float* nf   = (const float*)d_in[0];
    const float* ef   = (const float*)d_in[1];
    const float* W1   = (const float*)d_in[2];
    const float* b1   = (const float*)d_in[3];
    const float* W2   = (const float*)d_in[4];
    const float* b2   = (const float*)d_in[5];
    const float* wg   = (const float*)d_in[6];
    const float* bg   = (const float*)d_in[7];
    const float* Wh1  = (const float*)d_in[8];
    const float* bh1  = (const float*)d_in[9];
    const float* Wh2  = (const float*)d_in[10];
    const float* bh2  = (const float*)d_in[11];
    const float* Wout = (const float*)d_in[12];
    const float* bout = (const float*)d_in[13];
    const int*   send = (const int*)d_in[14];
    const int*   recv = (const int*)d_in[15];

    // workspace: [deg|idx4] zeroed (tail slots of the last padded tile must
    // gather row 0). efc placed LAST and gated on ws_size (fallback = R21).
    char* ws = (char*)d_ws;
    int*  deg   = (int*)ws;            ws += (size_t)N_AGENTS * 4;
    int4* idx4  = (int4*)ws;           ws += (size_t)EPAD * 16;
    size_t zero_bytes = (size_t)(ws - (char*)d_ws);
    int* rankb  = (int*)ws;            ws += (size_t)N_EDGES * 4;
    int* bsum   = (int*)ws;            ws += 32 * 4;
    int* off    = (int*)ws;            ws += (size_t)(N_AGENTS + 8) * 4;
    float* evals = (float*)ws;         ws += (size_t)EPAD * 4;
    f16* nf16   = (f16*)ws;            ws += (size_t)N_NODES * ND * 2;
    f16* F1     = (f16*)ws;            ws += (size_t)160 * 256 * 2;
    f16* F2     = (f16*)ws;            ws += (size_t)256 * 128 * 2;
    f16* F3     = (f16*)ws;            ws += (size_t)128 * 256 * 2;
    f16* F4     = (f16*)ws;            ws += (size_t)256 * 256 * 2;
    f16* msg    = (f16*)ws;            ws += (size_t)EPAD * 128 * 2;
    // optional CSR-ordered f16 edge-feature copy (+51.2 MB):
    f16* efc    = (f16*)ws;            ws += (size_t)EPAD * 32 * 2;
    size_t needed = (size_t)(ws - (char*)d_ws);
    if (needed > ws_size) efc = nullptr;   // fallback: exact R21 behavior

    hipMemsetAsync(d_ws, 0, zero_bytes, stream);

    compact_pack_kernel<<<N_EDGES / 256 + 84, 256, 0, stream>>>(
        recv, nf, nf16, rankb, deg, W1, W2, Wh1, Wh2, F1, F2, F3, F4);
    prefix_part<<<25, 1024, 0, stream>>>(deg, bsum);
    prefix_scan<<<25, 1024, 0, stream>>>(deg, bsum, off);
    scatter_kernel<<<N_EDGES / 256, 256, 0, stream>>>(
        recv, send, rankb, off, idx4, ef, efc);
    edge_mlp_mfma<<<512, 512, 0, stream>>>(
        nf16, ef, efc, F1, F2, b1, b2, wg, bg, (const int*)idx4,
        off + N_AGENTS, msg, evals);
    agg_agent_mfma<<<784, 1024, 0, stream>>>(
        off, evals, msg, F3, F4, bh1, bh2, Wout, bout, (float*)d_out);
}